// Round 2
// baseline (670.613 us; speedup 1.0000x reference)
//
#include <hip/hip_runtime.h>
#include <cfloat>
#include <cmath>

#define NB_CODE 1024
#define CODE_DIM 64
#define NROWS (32 * 8192)          // N*T = 262144
#define NTC ((size_t)NROWS * CODE_DIM)
#define TAU 0.05f                  // flag margin: conservative vs bf16-split error (~<=0.01)

typedef __attribute__((ext_vector_type(8))) short short8;
typedef __attribute__((ext_vector_type(4))) float f32x4;

// ws layout (32-bit words):
//   0..1023      counts (u32)
//   1024         loss_sum (f32 atomic)
//   1025         flag_count (u32)
//   1026..1027   pad
//   1028..2051   cnorm f32[1024]
//   2052..34819  cbh: ushort[1024*64]  bf16-hi of (-2*cb)
//   34820..67587 cbl: ushort[1024*64]  bf16-lo of (-2*cb)
//   67588..      flaglist u32[] (row<<10 | oldj)
#define W_LOSS 1024
#define W_FLAGCNT 1025
#define W_CNORM 1028
#define W_CBH 2052
#define W_CBL 34820
#define W_FLAGLIST 67588

__device__ inline unsigned short f2bf_rne(float x) {
    unsigned int u = __float_as_uint(x);
    unsigned int r = (u + 0x7FFFu + ((u >> 16) & 1u)) >> 16;
    return (unsigned short)r;
}
__device__ inline float bf2f(unsigned short h) {
    return __uint_as_float(((unsigned int)h) << 16);
}

// ---- prep: cnorm + bf16 hi/lo split of (-2*codebook) ----
__global__ void prep_kernel(const float* __restrict__ cb, float* __restrict__ ws) {
    int j = blockIdx.x * blockDim.x + threadIdx.x;
    if (j >= NB_CODE) return;
    float* cnorm = ws + W_CNORM;
    unsigned short* cbh = (unsigned short*)(ws + W_CBH);
    unsigned short* cbl = (unsigned short*)(ws + W_CBL);
    const float4* c4 = reinterpret_cast<const float4*>(cb + (size_t)j * CODE_DIM);
    float s = 0.f;
#pragma unroll
    for (int q = 0; q < 16; ++q) {
        float4 v = c4[q];
        float e[4] = {v.x, v.y, v.z, v.w};
#pragma unroll
        for (int u = 0; u < 4; ++u) {
            s = fmaf(e[u], e[u], s);
            float c2 = -2.f * e[u];
            unsigned short hb = f2bf_rne(c2);
            unsigned short lb = f2bf_rne(c2 - bf2f(hb));
            cbh[j * 64 + q * 4 + u] = hb;
            cbl[j * 64 + q * 4 + u] = lb;
        }
    }
    cnorm[j] = s;
}

// ---- main: MFMA distance + argmin + dequant + stats ----
__global__ __launch_bounds__(256) void vq_mfma_kernel(
    const float* __restrict__ x, const float* __restrict__ cb,
    float* __restrict__ ws, float* __restrict__ out, unsigned int flag_cap)
{
    __shared__ int lds_j[4 * 64];
    const int tid = threadIdx.x;
    const int w = tid >> 6, lane = tid & 63;
    const int lg = lane >> 4;          // lane group (k-group / D-row-group)
    const int li = lane & 15;          // A-row / B-col within tile
    const int wavebase = blockIdx.x * 256 + w * 64;

    const float* cnorm = ws + W_CNORM;
    const unsigned short* cbh = (const unsigned short*)(ws + W_CBH);
    const unsigned short* cbl = (const unsigned short*)(ws + W_CBL);
    unsigned int* counts = (unsigned int*)ws;
    float* loss_sum = ws + W_LOSS;
    unsigned int* flagcnt = (unsigned int*)ws + W_FLAGCNT;
    unsigned int* flaglist = (unsigned int*)ws + W_FLAGLIST;

    // --- load x rows, split to bf16 hi/lo fragments; accumulate sum(x^2) ---
    // A-frag layout for 16x16x32: row = lane&15, k = 32*f + 8*(lane>>4) + i
    short8 ah[4][2], al[4][2];
    float x2sum = 0.f;
#pragma unroll
    for (int rt = 0; rt < 4; ++rt) {
        const float* xr = x + (size_t)(wavebase + rt * 16 + li) * CODE_DIM;
#pragma unroll
        for (int f = 0; f < 2; ++f) {
            const float4* p = reinterpret_cast<const float4*>(xr + 32 * f + 8 * lg);
            float4 v0 = p[0], v1 = p[1];
            float e[8] = {v0.x, v0.y, v0.z, v0.w, v1.x, v1.y, v1.z, v1.w};
            short8 h8, l8;
#pragma unroll
            for (int i = 0; i < 8; ++i) {
                float xe = e[i];
                x2sum = fmaf(xe, xe, x2sum);
                unsigned short hb = f2bf_rne(xe);
                unsigned short lb = f2bf_rne(xe - bf2f(hb));
                h8[i] = (short)hb;
                l8[i] = (short)lb;
            }
            ah[rt][f] = h8;
            al[rt][f] = l8;
        }
    }

    float best[4][4], second[4][4];
    int bestj[4][4];
#pragma unroll
    for (int rt = 0; rt < 4; ++rt)
#pragma unroll
        for (int r = 0; r < 4; ++r) {
            best[rt][r] = FLT_MAX; second[rt][r] = FLT_MAX; bestj[rt][r] = 0;
        }

    // --- 64 code-tiles of 16 ---
    for (int t = 0; t < 64; ++t) {
        const int code = t * 16 + li;
        const unsigned short* bhp = cbh + (size_t)code * 64 + 8 * lg;
        const unsigned short* blp = cbl + (size_t)code * 64 + 8 * lg;
        short8 bh0 = *(const short8*)(bhp);
        short8 bh1 = *(const short8*)(bhp + 32);
        short8 bl0 = *(const short8*)(blp);
        short8 bl1 = *(const short8*)(blp + 32);
        float cn = cnorm[code];
        f32x4 cinit = {cn, cn, cn, cn};   // acc init = ||c||^2; MFMAs add -2*x.c
#pragma unroll
        for (int rt = 0; rt < 4; ++rt) {
            f32x4 acc = __builtin_amdgcn_mfma_f32_16x16x32_bf16(ah[rt][0], bh0, cinit, 0, 0, 0);
            acc = __builtin_amdgcn_mfma_f32_16x16x32_bf16(ah[rt][1], bh1, acc, 0, 0, 0);
            acc = __builtin_amdgcn_mfma_f32_16x16x32_bf16(al[rt][0], bh0, acc, 0, 0, 0);
            acc = __builtin_amdgcn_mfma_f32_16x16x32_bf16(al[rt][1], bh1, acc, 0, 0, 0);
            acc = __builtin_amdgcn_mfma_f32_16x16x32_bf16(ah[rt][0], bl0, acc, 0, 0, 0);
            acc = __builtin_amdgcn_mfma_f32_16x16x32_bf16(ah[rt][1], bl1, acc, 0, 0, 0);
            acc = __builtin_amdgcn_mfma_f32_16x16x32_bf16(al[rt][0], bl0, acc, 0, 0, 0);
            acc = __builtin_amdgcn_mfma_f32_16x16x32_bf16(al[rt][1], bl1, acc, 0, 0, 0);
#pragma unroll
            for (int r = 0; r < 4; ++r) {
                float d = acc[r];
                float mx = fmaxf(best[rt][r], d);
                second[rt][r] = fminf(second[rt][r], mx);
                bool take = d < best[rt][r];
                best[rt][r] = take ? d : best[rt][r];
                bestj[rt][r] = take ? code : bestj[rt][r];
            }
        }
    }

    // --- per-row reduce across the 16 lanes of each group (masks 1,2,4,8) ---
    // D layout: row_in_tile = 4*lg + r, col = li  -> row's 16 cols live in lanes 16*lg..16*lg+15
#pragma unroll
    for (int rt = 0; rt < 4; ++rt)
#pragma unroll
        for (int r = 0; r < 4; ++r) {
            float b = best[rt][r], s = second[rt][r];
            int j = bestj[rt][r];
#pragma unroll
            for (int m = 1; m <= 8; m <<= 1) {
                float ob = __shfl_xor(b, m, 64);
                float os = __shfl_xor(s, m, 64);
                int   oj = __shfl_xor(j, m, 64);
                float s2 = fminf(fminf(s, os), fmaxf(b, ob));
                bool take = (ob < b) || (ob == b && oj < j);
                b = take ? ob : b;
                j = take ? oj : j;
                s = s2;
            }
            best[rt][r] = b; second[rt][r] = s; bestj[rt][r] = j;
        }

    // --- stats, flags, stash indices ---
    float lsum = x2sum;           // every x element counted exactly once across the wave
    if (li == 0) {
#pragma unroll
        for (int rt = 0; rt < 4; ++rt)
#pragma unroll
            for (int r = 0; r < 4; ++r) {
                int rowin = rt * 16 + lg * 4 + r;
                int j = bestj[rt][r];
                lds_j[w * 64 + rowin] = j;
                atomicAdd(&counts[j], 1u);
                lsum += best[rt][r];      // loss_row = ||x||^2 + (||c||^2 - 2 x.c)
                if (second[rt][r] - best[rt][r] <= TAU) {
                    unsigned pos = atomicAdd(flagcnt, 1u);
                    if (pos < flag_cap)
                        flaglist[pos] = ((unsigned)(wavebase + rowin) << 10) | (unsigned)j;
                }
            }
    }
#pragma unroll
    for (int m = 32; m >= 1; m >>= 1) lsum += __shfl_down(lsum, m, 64);
    if (lane == 0) atomicAdd(loss_sum, lsum);

    __syncthreads();

    // --- dequant write: 4 rows/iter, float4 per lane ---
    for (int it = 0; it < 16; ++it) {
        int rowin = it * 4 + lg;
        int j = lds_j[w * 64 + rowin];
        float4 v = *reinterpret_cast<const float4*>(cb + (size_t)j * CODE_DIM + li * 4);
        *reinterpret_cast<float4*>(out + (size_t)(wavebase + rowin) * CODE_DIM + li * 4) = v;
    }
}

// ---- exact f32 re-solve for flagged (near-tie) rows ----
__global__ __launch_bounds__(256) void fixup_kernel(
    const float* __restrict__ x, const float* __restrict__ cb,
    float* __restrict__ ws, float* __restrict__ out, unsigned int flag_cap)
{
    unsigned nf = *((unsigned*)ws + W_FLAGCNT);
    if (nf > flag_cap) nf = flag_cap;
    const float* cnorm = ws + W_CNORM;
    unsigned* flaglist = (unsigned*)ws + W_FLAGLIST;
    unsigned* counts = (unsigned*)ws;

    for (unsigned idx = blockIdx.x * blockDim.x + threadIdx.x; idx < nf;
         idx += gridDim.x * blockDim.x) {
        unsigned e = flaglist[idx];
        int row = (int)(e >> 10);
        int oldj = (int)(e & 1023u);

        float xr[CODE_DIM];
        const float4* x4 = reinterpret_cast<const float4*>(x + (size_t)row * CODE_DIM);
#pragma unroll
        for (int q = 0; q < 16; ++q) {
            float4 v = x4[q];
            xr[4 * q + 0] = v.x; xr[4 * q + 1] = v.y;
            xr[4 * q + 2] = v.z; xr[4 * q + 3] = v.w;
        }
        float bestv = FLT_MAX; int bj = 0;
        for (int j = 0; j < NB_CODE; ++j) {
            const float* c = cb + (size_t)j * CODE_DIM;
            float d0 = 0.f, d1 = 0.f, d2 = 0.f, d3 = 0.f;
#pragma unroll
            for (int k = 0; k < CODE_DIM; k += 4) {
                d0 = fmaf(xr[k + 0], c[k + 0], d0);
                d1 = fmaf(xr[k + 1], c[k + 1], d1);
                d2 = fmaf(xr[k + 2], c[k + 2], d2);
                d3 = fmaf(xr[k + 3], c[k + 3], d3);
            }
            float dist = fmaf(-2.f, (d0 + d1) + (d2 + d3), cnorm[j]);
            if (dist < bestv) { bestv = dist; bj = j; }
        }
        if (bj != oldj) {
#pragma unroll
            for (int k = 0; k < CODE_DIM; k += 4)
                *reinterpret_cast<float4*>(out + (size_t)row * CODE_DIM + k) =
                    *reinterpret_cast<const float4*>(cb + (size_t)bj * CODE_DIM + k);
            atomicAdd(&counts[bj], 1u);
            atomicAdd(&counts[oldj], (unsigned)-1);
        }
    }
}

__global__ void finalize_kernel(const unsigned int* __restrict__ counts,
                                const float* __restrict__ loss_sum,
                                float* __restrict__ out)
{
    __shared__ float red[NB_CODE];
    int t = threadIdx.x;
    float p = (float)counts[t] / (float)NROWS;
    red[t] = p * logf(p + 1e-7f);
    __syncthreads();
    for (int s = NB_CODE / 2; s > 0; s >>= 1) {
        if (t < s) red[t] += red[t + s];
        __syncthreads();
    }
    if (t == 0) {
        out[NTC + 0] = *loss_sum / (float)NTC;
        out[NTC + 1] = expf(-red[0]);
    }
}

extern "C" void kernel_launch(void* const* d_in, const int* in_sizes, int n_in,
                              void* d_out, int out_size, void* d_ws, size_t ws_size,
                              hipStream_t stream) {
    const float* x  = (const float*)d_in[0];
    const float* cb = (const float*)d_in[1];
    float* out = (float*)d_out;
    float* ws = (float*)d_ws;

    unsigned flag_cap = 0;
    size_t words = ws_size / 4;
    if (words > (size_t)W_FLAGLIST) flag_cap = (unsigned)(words - W_FLAGLIST);
    if (flag_cap > NROWS) flag_cap = NROWS;

    // zero counts + loss + flagcnt each call (ws not re-poisoned between replays)
    hipMemsetAsync(d_ws, 0, 1028 * sizeof(float), stream);

    prep_kernel<<<NB_CODE / 256, 256, 0, stream>>>(cb, ws);
    vq_mfma_kernel<<<NROWS / 256, 256, 0, stream>>>(x, cb, ws, out, flag_cap);
    fixup_kernel<<<256, 256, 0, stream>>>(x, cb, ws, out, flag_cap);
    finalize_kernel<<<1, NB_CODE, 0, stream>>>((unsigned int*)ws, ws + W_LOSS, out);
}

// Round 3
// 339.149 us; speedup vs baseline: 1.9773x; 1.9773x over previous
//
#include <hip/hip_runtime.h>
#include <cfloat>
#include <cmath>

#define NB_CODE 1024
#define CODE_DIM 64
#define NROWS (32 * 8192)          // N*T = 262144
#define NTC ((size_t)NROWS * CODE_DIM)
#define TAU 0.02f                  // flag margin >= ~4x bf16-split+dropped-ll error bound

typedef __attribute__((ext_vector_type(8))) short short8;
typedef __attribute__((ext_vector_type(4))) float f32x4;

// ws layout (32-bit words):
//   0..1023      counts (u32)
//   1024         loss_sum (f32 atomic)
//   1025         flag_count (u32)
//   1026..1027   pad
//   1028..2051   cnorm f32[1024]
//   2052..34819  cbh: ushort[1024*64]  bf16-hi of (-2*cb)
//   34820..67587 cbl: ushort[1024*64]  bf16-lo of (-2*cb)
//   67588..      flaglist u32[] (row<<10 | oldj)
#define W_LOSS 1024
#define W_FLAGCNT 1025
#define W_CNORM 1028
#define W_CBH 2052
#define W_CBL 34820
#define W_FLAGLIST 67588

__device__ inline unsigned short f2bf_rne(float x) {
    unsigned int u = __float_as_uint(x);
    unsigned int r = (u + 0x7FFFu + ((u >> 16) & 1u)) >> 16;
    return (unsigned short)r;
}
__device__ inline float bf2f(unsigned short h) {
    return __uint_as_float(((unsigned int)h) << 16);
}

// ---- prep: cnorm + bf16 hi/lo split of (-2*codebook) ----
__global__ void prep_kernel(const float* __restrict__ cb, float* __restrict__ ws) {
    int j = blockIdx.x * blockDim.x + threadIdx.x;
    if (j >= NB_CODE) return;
    float* cnorm = ws + W_CNORM;
    unsigned short* cbh = (unsigned short*)(ws + W_CBH);
    unsigned short* cbl = (unsigned short*)(ws + W_CBL);
    const float4* c4 = reinterpret_cast<const float4*>(cb + (size_t)j * CODE_DIM);
    float s = 0.f;
#pragma unroll
    for (int q = 0; q < 16; ++q) {
        float4 v = c4[q];
        float e[4] = {v.x, v.y, v.z, v.w};
#pragma unroll
        for (int u = 0; u < 4; ++u) {
            s = fmaf(e[u], e[u], s);
            float c2 = -2.f * e[u];
            unsigned short hb = f2bf_rne(c2);
            unsigned short lb = f2bf_rne(c2 - bf2f(hb));
            cbh[j * 64 + q * 4 + u] = hb;
            cbl[j * 64 + q * 4 + u] = lb;
        }
    }
    cnorm[j] = s;
}

__device__ inline void load_btile(const unsigned short* __restrict__ cbh,
                                  const unsigned short* __restrict__ cbl,
                                  const float* __restrict__ cnorm,
                                  int code, int lg,
                                  short8& bh0, short8& bh1, short8& bl0, short8& bl1,
                                  float& cn)
{
    const unsigned short* bhp = cbh + (size_t)code * 64 + 8 * lg;
    const unsigned short* blp = cbl + (size_t)code * 64 + 8 * lg;
    bh0 = *(const short8*)(bhp);
    bh1 = *(const short8*)(bhp + 32);
    bl0 = *(const short8*)(blp);
    bl1 = *(const short8*)(blp + 32);
    cn = cnorm[code];
}

// ---- main: MFMA distance + argmin + dequant + stats ----
__global__ __launch_bounds__(256) void vq_mfma_kernel(
    const float* __restrict__ x, const float* __restrict__ cb,
    float* __restrict__ ws, float* __restrict__ out, unsigned int flag_cap)
{
    __shared__ int lds_j[4 * 64];
    const int tid = threadIdx.x;
    const int w = tid >> 6, lane = tid & 63;
    const int lg = lane >> 4;          // lane group (k-group / D-row-group)
    const int li = lane & 15;          // A-row / B-col within tile
    const int wavebase = blockIdx.x * 256 + w * 64;

    const float* cnorm = ws + W_CNORM;
    const unsigned short* cbh = (const unsigned short*)(ws + W_CBH);
    const unsigned short* cbl = (const unsigned short*)(ws + W_CBL);
    unsigned int* counts = (unsigned int*)ws;
    float* loss_sum = ws + W_LOSS;
    unsigned int* flagcnt = (unsigned int*)ws + W_FLAGCNT;
    unsigned int* flaglist = (unsigned int*)ws + W_FLAGLIST;

    // --- load x rows, split to bf16 hi/lo fragments; accumulate sum(x^2) ---
    // A-frag layout for 16x16x32: row = lane&15, k = 32*f + 8*(lane>>4) + i
    short8 ah[4][2], al[4][2];
    float x2sum = 0.f;
#pragma unroll
    for (int rt = 0; rt < 4; ++rt) {
        const float* xr = x + (size_t)(wavebase + rt * 16 + li) * CODE_DIM;
#pragma unroll
        for (int f = 0; f < 2; ++f) {
            const float4* p = reinterpret_cast<const float4*>(xr + 32 * f + 8 * lg);
            float4 v0 = p[0], v1 = p[1];
            float e[8] = {v0.x, v0.y, v0.z, v0.w, v1.x, v1.y, v1.z, v1.w};
            short8 h8, l8;
#pragma unroll
            for (int i = 0; i < 8; ++i) {
                float xe = e[i];
                x2sum = fmaf(xe, xe, x2sum);
                unsigned short hb = f2bf_rne(xe);
                unsigned short lb = f2bf_rne(xe - bf2f(hb));
                h8[i] = (short)hb;
                l8[i] = (short)lb;
            }
            ah[rt][f] = h8;
            al[rt][f] = l8;
        }
    }

    float best[4][4], second[4][4];
    int bestj[4][4];
#pragma unroll
    for (int rt = 0; rt < 4; ++rt)
#pragma unroll
        for (int r = 0; r < 4; ++r) {
            best[rt][r] = FLT_MAX; second[rt][r] = FLT_MAX; bestj[rt][r] = 0;
        }

    // --- 64 code-tiles of 16, register-double-buffered B stream ---
    short8 bh0, bh1, bl0, bl1; float cn;
    load_btile(cbh, cbl, cnorm, li, lg, bh0, bh1, bl0, bl1, cn);
    for (int t = 0; t < 64; ++t) {
        short8 nh0, nh1, nl0, nl1; float ncn;
        load_btile(cbh, cbl, cnorm, ((t + 1) & 63) * 16 + li, lg, nh0, nh1, nl0, nl1, ncn);
        const int code = t * 16 + li;
        f32x4 cinit = {cn, cn, cn, cn};   // acc init = ||c||^2; MFMAs add -2*x.c
#pragma unroll
        for (int rt = 0; rt < 4; ++rt) {
            // hi*hi + lo*hi + hi*lo  (lo*lo dropped: ~8e-4 << TAU)
            f32x4 acc = __builtin_amdgcn_mfma_f32_16x16x32_bf16(ah[rt][0], bh0, cinit, 0, 0, 0);
            acc = __builtin_amdgcn_mfma_f32_16x16x32_bf16(ah[rt][1], bh1, acc, 0, 0, 0);
            acc = __builtin_amdgcn_mfma_f32_16x16x32_bf16(al[rt][0], bh0, acc, 0, 0, 0);
            acc = __builtin_amdgcn_mfma_f32_16x16x32_bf16(al[rt][1], bh1, acc, 0, 0, 0);
            acc = __builtin_amdgcn_mfma_f32_16x16x32_bf16(ah[rt][0], bl0, acc, 0, 0, 0);
            acc = __builtin_amdgcn_mfma_f32_16x16x32_bf16(ah[rt][1], bl1, acc, 0, 0, 0);
#pragma unroll
            for (int r = 0; r < 4; ++r) {
                float d = acc[r];
                float mx = fmaxf(best[rt][r], d);
                second[rt][r] = fminf(second[rt][r], mx);
                bool take = d < best[rt][r];
                best[rt][r] = take ? d : best[rt][r];
                bestj[rt][r] = take ? code : bestj[rt][r];
            }
        }
        bh0 = nh0; bh1 = nh1; bl0 = nl0; bl1 = nl1; cn = ncn;
    }

    // --- per-row reduce across the 16 lanes of each group (masks 1,2,4,8) ---
#pragma unroll
    for (int rt = 0; rt < 4; ++rt)
#pragma unroll
        for (int r = 0; r < 4; ++r) {
            float b = best[rt][r], s = second[rt][r];
            int j = bestj[rt][r];
#pragma unroll
            for (int m = 1; m <= 8; m <<= 1) {
                float ob = __shfl_xor(b, m, 64);
                float os = __shfl_xor(s, m, 64);
                int   oj = __shfl_xor(j, m, 64);
                float s2 = fminf(fminf(s, os), fmaxf(b, ob));
                bool take = (ob < b) || (ob == b && oj < j);
                b = take ? ob : b;
                j = take ? oj : j;
                s = s2;
            }
            best[rt][r] = b; second[rt][r] = s; bestj[rt][r] = j;
        }

    // --- stats, flags, stash indices ---
    float lsum = x2sum;           // every x element counted exactly once across the wave
    if (li == 0) {
#pragma unroll
        for (int rt = 0; rt < 4; ++rt)
#pragma unroll
            for (int r = 0; r < 4; ++r) {
                int rowin = rt * 16 + lg * 4 + r;
                int j = bestj[rt][r];
                lds_j[w * 64 + rowin] = j;
                atomicAdd(&counts[j], 1u);
                lsum += best[rt][r];      // loss_row = ||x||^2 + (||c||^2 - 2 x.c)
                if (second[rt][r] - best[rt][r] <= TAU) {
                    unsigned pos = atomicAdd(flagcnt, 1u);
                    if (pos < flag_cap)
                        flaglist[pos] = ((unsigned)(wavebase + rowin) << 10) | (unsigned)j;
                }
            }
    }
#pragma unroll
    for (int m = 32; m >= 1; m >>= 1) lsum += __shfl_down(lsum, m, 64);
    if (lane == 0) atomicAdd(loss_sum, lsum);

    __syncthreads();

    // --- dequant write: 4 rows/iter, float4 per lane ---
    for (int it = 0; it < 16; ++it) {
        int rowin = it * 4 + lg;
        int j = lds_j[w * 64 + rowin];
        float4 v = *reinterpret_cast<const float4*>(cb + (size_t)j * CODE_DIM + li * 4);
        *reinterpret_cast<float4*>(out + (size_t)(wavebase + rowin) * CODE_DIM + li * 4) = v;
    }
}

// ---- exact f32 re-solve for flagged (near-tie) rows: ONE WAVE PER ROW ----
__global__ __launch_bounds__(256) void fixup_kernel(
    const float* __restrict__ x, const float* __restrict__ cb,
    float* __restrict__ ws, float* __restrict__ out, unsigned int flag_cap)
{
    unsigned nf = *((unsigned*)ws + W_FLAGCNT);
    if (nf > flag_cap) nf = flag_cap;
    const float* cnorm = ws + W_CNORM;
    unsigned* flaglist = (unsigned*)ws + W_FLAGLIST;
    unsigned* counts = (unsigned*)ws;

    const int lane = threadIdx.x & 63;
    const unsigned wave_id = (blockIdx.x * blockDim.x + threadIdx.x) >> 6;
    const unsigned nwaves = (gridDim.x * blockDim.x) >> 6;

    for (unsigned idx = wave_id; idx < nf; idx += nwaves) {
        unsigned e = flaglist[idx];
        int row = (int)(e >> 10);
        int oldj = (int)(e & 1023u);

        // whole wave loads the same x row (broadcast)
        float xr[CODE_DIM];
        const float4* x4 = reinterpret_cast<const float4*>(x + (size_t)row * CODE_DIM);
#pragma unroll
        for (int q = 0; q < 16; ++q) {
            float4 v = x4[q];
            xr[4 * q + 0] = v.x; xr[4 * q + 1] = v.y;
            xr[4 * q + 2] = v.z; xr[4 * q + 3] = v.w;
        }

        // lane scans codes [16*lane, 16*lane+16) ascending -> per-lane first-occurrence kept
        float bestv = FLT_MAX; int bj = 0x7fffffff;
        for (int t = 0; t < 16; ++t) {
            int j = lane * 16 + t;
            const float* c = cb + (size_t)j * CODE_DIM;
            float d0 = 0.f, d1 = 0.f, d2 = 0.f, d3 = 0.f;
#pragma unroll
            for (int k = 0; k < CODE_DIM; k += 4) {
                d0 = fmaf(xr[k + 0], c[k + 0], d0);
                d1 = fmaf(xr[k + 1], c[k + 1], d1);
                d2 = fmaf(xr[k + 2], c[k + 2], d2);
                d3 = fmaf(xr[k + 3], c[k + 3], d3);
            }
            float dist = fmaf(-2.f, (d0 + d1) + (d2 + d3), cnorm[j]);
            if (dist < bestv) { bestv = dist; bj = j; }
        }
        // cross-lane argmin with lowest-index tie-break
#pragma unroll
        for (int m = 1; m <= 32; m <<= 1) {
            float ob = __shfl_xor(bestv, m, 64);
            int   oj = __shfl_xor(bj, m, 64);
            bool take = (ob < bestv) || (ob == bestv && oj < bj);
            bestv = take ? ob : bestv;
            bj = take ? oj : bestv == bestv ? (take ? oj : bj) : bj;  // avoid compiler confusion
            if (take) bj = oj;
        }

        if (bj != oldj) {
            // rewrite out row (16 lanes x float4) and patch counts once
            if (lane < 16) {
                *reinterpret_cast<float4*>(out + (size_t)row * CODE_DIM + lane * 4) =
                    *reinterpret_cast<const float4*>(cb + (size_t)bj * CODE_DIM + lane * 4);
            }
            if (lane == 0) {
                atomicAdd(&counts[bj], 1u);
                atomicAdd(&counts[oldj], (unsigned)-1);
            }
        }
    }
}

__global__ void finalize_kernel(const unsigned int* __restrict__ counts,
                                const float* __restrict__ loss_sum,
                                float* __restrict__ out)
{
    __shared__ float red[NB_CODE];
    int t = threadIdx.x;
    float p = (float)counts[t] / (float)NROWS;
    red[t] = p * logf(p + 1e-7f);
    __syncthreads();
    for (int s = NB_CODE / 2; s > 0; s >>= 1) {
        if (t < s) red[t] += red[t + s];
        __syncthreads();
    }
    if (t == 0) {
        out[NTC + 0] = *loss_sum / (float)NTC;
        out[NTC + 1] = expf(-red[0]);
    }
}

extern "C" void kernel_launch(void* const* d_in, const int* in_sizes, int n_in,
                              void* d_out, int out_size, void* d_ws, size_t ws_size,
                              hipStream_t stream) {
    const float* x  = (const float*)d_in[0];
    const float* cb = (const float*)d_in[1];
    float* out = (float*)d_out;
    float* ws = (float*)d_ws;

    unsigned flag_cap = 0;
    size_t words = ws_size / 4;
    if (words > (size_t)W_FLAGLIST) flag_cap = (unsigned)(words - W_FLAGLIST);
    if (flag_cap > NROWS) flag_cap = NROWS;

    // zero counts + loss + flagcnt each call (ws not re-poisoned between replays)
    hipMemsetAsync(d_ws, 0, 1028 * sizeof(float), stream);

    prep_kernel<<<NB_CODE / 256, 256, 0, stream>>>(cb, ws);
    vq_mfma_kernel<<<NROWS / 256, 256, 0, stream>>>(x, cb, ws, out, flag_cap);
    fixup_kernel<<<256, 256, 0, stream>>>(x, cb, ws, out, flag_cap);
    finalize_kernel<<<1, NB_CODE, 0, stream>>>((unsigned int*)ws, ws + W_LOSS, out);
}

// Round 4
// 291.515 us; speedup vs baseline: 2.3004x; 1.1634x over previous
//
#include <hip/hip_runtime.h>
#include <cfloat>
#include <cmath>

#define NB_CODE 1024
#define CODE_DIM 64
#define NROWS (32 * 8192)          // N*T = 262144
#define NTC ((size_t)NROWS * CODE_DIM)
#define TAU 0.02f                  // flag margin >= ~4x bf16-split+dropped-ll error bound

typedef __attribute__((ext_vector_type(8))) short short8;
typedef __attribute__((ext_vector_type(4))) float f32x4;

// ws layout (32-bit words):
//   0..1023      counts (u32)
//   1024         loss_sum (f32 atomic)
//   1025         flag_count (u32)
//   1026..1027   pad
//   1028..2051   cnorm f32[1024]
//   2052..67587  cbp: fragment-major bf16 split of (-2*cb), 256 KB
//                entry e = ((t*4 + chunk)*64 + lane), 16B each;
//                chunk 0,1 = hi (k 0..31 / 32..63), chunk 2,3 = lo
//   67588..      flaglist u32[] (row<<10 | oldj)
#define W_LOSS 1024
#define W_FLAGCNT 1025
#define W_CNORM 1028
#define W_CBP 2052
#define W_FLAGLIST 67588

__device__ inline unsigned short f2bf_rne(float x) {
    unsigned int u = __float_as_uint(x);
    unsigned int r = (u + 0x7FFFu + ((u >> 16) & 1u)) >> 16;
    return (unsigned short)r;
}
__device__ inline float bf2f(unsigned short h) {
    return __uint_as_float(((unsigned int)h) << 16);
}

// ---- prep: cnorm + fragment-major bf16 hi/lo split of (-2*codebook) ----
// B-frag mapping for 16x16x32 (verified rounds 1-3): lane = lg*16+li holds
// col=li, k = 32*f + 8*lg + i. Fragment-major: chunk f (hi) / 2+f (lo),
// entry = ((t*4+chunk)*64 + lg*16 + li) -> a wave's chunk load is 1KB contiguous.
__global__ void prep_kernel(const float* __restrict__ cb, float* __restrict__ ws) {
    int j = blockIdx.x * blockDim.x + threadIdx.x;
    if (j >= NB_CODE) return;
    float* cnorm = ws + W_CNORM;
    unsigned short* cbp = (unsigned short*)(ws + W_CBP);
    const int t = j >> 4, li = j & 15;

    float c2v[CODE_DIM];
    const float4* c4 = reinterpret_cast<const float4*>(cb + (size_t)j * CODE_DIM);
    float s = 0.f;
#pragma unroll
    for (int q = 0; q < 16; ++q) {
        float4 v = c4[q];
        float e[4] = {v.x, v.y, v.z, v.w};
#pragma unroll
        for (int u = 0; u < 4; ++u) {
            s = fmaf(e[u], e[u], s);
            c2v[q * 4 + u] = -2.f * e[u];
        }
    }
    cnorm[j] = s;

#pragma unroll
    for (int f = 0; f < 2; ++f) {
#pragma unroll
        for (int lg = 0; lg < 4; ++lg) {
            short8 h8, l8;
#pragma unroll
            for (int i = 0; i < 8; ++i) {
                float c2 = c2v[32 * f + 8 * lg + i];
                unsigned short hb = f2bf_rne(c2);
                unsigned short lb = f2bf_rne(c2 - bf2f(hb));
                h8[i] = (short)hb;
                l8[i] = (short)lb;
            }
            size_t ehi = ((size_t)(t * 4 + f) * 64 + lg * 16 + li);
            size_t elo = ((size_t)(t * 4 + 2 + f) * 64 + lg * 16 + li);
            *reinterpret_cast<short8*>(cbp + ehi * 8) = h8;
            *reinterpret_cast<short8*>(cbp + elo * 8) = l8;
        }
    }
}

struct BTile { short8 b0, b1, b2, b3; float cn; };

__device__ inline void load_tile(const unsigned short* __restrict__ cbp,
                                 const float* __restrict__ cnorm,
                                 int t, int lane, int li, BTile& T)
{
    const unsigned short* base = cbp + ((size_t)t * 4 * 64 + lane) * 8;
    T.b0 = *reinterpret_cast<const short8*>(base);            // chunk 0: hi k0..31
    T.b1 = *reinterpret_cast<const short8*>(base + 64 * 8);   // chunk 1: hi k32..63
    T.b2 = *reinterpret_cast<const short8*>(base + 128 * 8);  // chunk 2: lo k0..31
    T.b3 = *reinterpret_cast<const short8*>(base + 192 * 8);  // chunk 3: lo k32..63
    T.cn = cnorm[t * 16 + li];
}

// ---- main: MFMA distance + argmin + dequant + stats ----
__global__ __launch_bounds__(256) void vq_mfma_kernel(
    const float* __restrict__ x, const float* __restrict__ cb,
    float* __restrict__ ws, float* __restrict__ out, unsigned int flag_cap)
{
    __shared__ int lds_j[4 * 64];
    const int tid = threadIdx.x;
    const int w = tid >> 6, lane = tid & 63;
    const int lg = lane >> 4;          // lane group (k-group / D-row-group)
    const int li = lane & 15;          // A-row / B-col within tile
    const int wavebase = blockIdx.x * 256 + w * 64;

    const float* cnorm = ws + W_CNORM;
    const unsigned short* cbp = (const unsigned short*)(ws + W_CBP);
    unsigned int* counts = (unsigned int*)ws;
    float* loss_sum = ws + W_LOSS;
    unsigned int* flagcnt = (unsigned int*)ws + W_FLAGCNT;
    unsigned int* flaglist = (unsigned int*)ws + W_FLAGLIST;

    // --- load x rows, split to bf16 hi/lo fragments; accumulate sum(x^2) ---
    // A-frag layout for 16x16x32: row = lane&15, k = 32*f + 8*(lane>>4) + i
    short8 ah[4][2], al[4][2];
    float x2sum = 0.f;
#pragma unroll
    for (int rt = 0; rt < 4; ++rt) {
        const float* xr = x + (size_t)(wavebase + rt * 16 + li) * CODE_DIM;
#pragma unroll
        for (int f = 0; f < 2; ++f) {
            const float4* p = reinterpret_cast<const float4*>(xr + 32 * f + 8 * lg);
            float4 v0 = p[0], v1 = p[1];
            float e[8] = {v0.x, v0.y, v0.z, v0.w, v1.x, v1.y, v1.z, v1.w};
            short8 h8, l8;
#pragma unroll
            for (int i = 0; i < 8; ++i) {
                float xe = e[i];
                x2sum = fmaf(xe, xe, x2sum);
                unsigned short hb = f2bf_rne(xe);
                unsigned short lb = f2bf_rne(xe - bf2f(hb));
                h8[i] = (short)hb;
                l8[i] = (short)lb;
            }
            ah[rt][f] = h8;
            al[rt][f] = l8;
        }
    }

    float best[4][4], second[4][4];
    int bestj[4][4];
#pragma unroll
    for (int rt = 0; rt < 4; ++rt)
#pragma unroll
        for (int r = 0; r < 4; ++r) {
            best[rt][r] = FLT_MAX; second[rt][r] = FLT_MAX; bestj[rt][r] = 0;
        }

    // --- 64 code-tiles of 16; depth-2 register double-buffer on coalesced B ---
    BTile A, B;
    load_tile(cbp, cnorm, 0, lane, li, A);
    load_tile(cbp, cnorm, 1, lane, li, B);

#define COMPUTE_TILE(T, tt)                                                          \
    {                                                                                \
        const int code = (tt) * 16 + li;                                             \
        f32x4 cinit = {T.cn, T.cn, T.cn, T.cn};                                      \
        _Pragma("unroll")                                                            \
        for (int rt = 0; rt < 4; ++rt) {                                             \
            f32x4 acc = __builtin_amdgcn_mfma_f32_16x16x32_bf16(ah[rt][0], T.b0, cinit, 0, 0, 0); \
            acc = __builtin_amdgcn_mfma_f32_16x16x32_bf16(ah[rt][1], T.b1, acc, 0, 0, 0); \
            acc = __builtin_amdgcn_mfma_f32_16x16x32_bf16(al[rt][0], T.b0, acc, 0, 0, 0); \
            acc = __builtin_amdgcn_mfma_f32_16x16x32_bf16(al[rt][1], T.b1, acc, 0, 0, 0); \
            acc = __builtin_amdgcn_mfma_f32_16x16x32_bf16(ah[rt][0], T.b2, acc, 0, 0, 0); \
            acc = __builtin_amdgcn_mfma_f32_16x16x32_bf16(ah[rt][1], T.b3, acc, 0, 0, 0); \
            _Pragma("unroll")                                                        \
            for (int r = 0; r < 4; ++r) {                                            \
                float d = acc[r];                                                    \
                float mx = fmaxf(best[rt][r], d);                                    \
                second[rt][r] = fminf(second[rt][r], mx);                            \
                bool take = d < best[rt][r];                                         \
                best[rt][r] = take ? d : best[rt][r];                                \
                bestj[rt][r] = take ? code : bestj[rt][r];                           \
            }                                                                        \
        }                                                                            \
    }

    for (int t = 0; t < 64; t += 2) {
        COMPUTE_TILE(A, t);
        load_tile(cbp, cnorm, (t + 2) & 63, lane, li, A);   // prefetch t+2
        COMPUTE_TILE(B, t + 1);
        load_tile(cbp, cnorm, (t + 3) & 63, lane, li, B);   // prefetch t+3
    }
#undef COMPUTE_TILE

    // --- per-row reduce across the 16 lanes of each group (masks 1,2,4,8) ---
#pragma unroll
    for (int rt = 0; rt < 4; ++rt)
#pragma unroll
        for (int r = 0; r < 4; ++r) {
            float b = best[rt][r], s = second[rt][r];
            int j = bestj[rt][r];
#pragma unroll
            for (int m = 1; m <= 8; m <<= 1) {
                float ob = __shfl_xor(b, m, 64);
                float os = __shfl_xor(s, m, 64);
                int   oj = __shfl_xor(j, m, 64);
                float s2 = fminf(fminf(s, os), fmaxf(b, ob));
                bool take = (ob < b) || (ob == b && oj < j);
                b = take ? ob : b;
                j = take ? oj : j;
                s = s2;
            }
            best[rt][r] = b; second[rt][r] = s; bestj[rt][r] = j;
        }

    // --- stats, flags, stash indices ---
    float lsum = x2sum;           // every x element counted exactly once across the wave
    if (li == 0) {
#pragma unroll
        for (int rt = 0; rt < 4; ++rt)
#pragma unroll
            for (int r = 0; r < 4; ++r) {
                int rowin = rt * 16 + lg * 4 + r;
                int j = bestj[rt][r];
                lds_j[w * 64 + rowin] = j;
                atomicAdd(&counts[j], 1u);
                lsum += best[rt][r];      // loss_row = ||x||^2 + (||c||^2 - 2 x.c)
                if (second[rt][r] - best[rt][r] <= TAU) {
                    unsigned pos = atomicAdd(flagcnt, 1u);
                    if (pos < flag_cap)
                        flaglist[pos] = ((unsigned)(wavebase + rowin) << 10) | (unsigned)j;
                }
            }
    }
#pragma unroll
    for (int m = 32; m >= 1; m >>= 1) lsum += __shfl_down(lsum, m, 64);
    if (lane == 0) atomicAdd(loss_sum, lsum);

    __syncthreads();

    // --- dequant write: 4 rows/iter, float4 per lane ---
    for (int it = 0; it < 16; ++it) {
        int rowin = it * 4 + lg;
        int j = lds_j[w * 64 + rowin];
        float4 v = *reinterpret_cast<const float4*>(cb + (size_t)j * CODE_DIM + li * 4);
        *reinterpret_cast<float4*>(out + (size_t)(wavebase + rowin) * CODE_DIM + li * 4) = v;
    }
}

// ---- exact f32 re-solve for flagged (near-tie) rows: ONE WAVE PER ROW ----
__global__ __launch_bounds__(256) void fixup_kernel(
    const float* __restrict__ x, const float* __restrict__ cb,
    float* __restrict__ ws, float* __restrict__ out, unsigned int flag_cap)
{
    unsigned nf = *((unsigned*)ws + W_FLAGCNT);
    if (nf > flag_cap) nf = flag_cap;
    const float* cnorm = ws + W_CNORM;
    unsigned* flaglist = (unsigned*)ws + W_FLAGLIST;
    unsigned* counts = (unsigned*)ws;

    const int lane = threadIdx.x & 63;
    const unsigned wave_id = (blockIdx.x * blockDim.x + threadIdx.x) >> 6;
    const unsigned nwaves = (gridDim.x * blockDim.x) >> 6;

    for (unsigned idx = wave_id; idx < nf; idx += nwaves) {
        unsigned e = flaglist[idx];
        int row = (int)(e >> 10);
        int oldj = (int)(e & 1023u);

        // whole wave loads the same x row (broadcast)
        float xr[CODE_DIM];
        const float4* x4 = reinterpret_cast<const float4*>(x + (size_t)row * CODE_DIM);
#pragma unroll
        for (int q = 0; q < 16; ++q) {
            float4 v = x4[q];
            xr[4 * q + 0] = v.x; xr[4 * q + 1] = v.y;
            xr[4 * q + 2] = v.z; xr[4 * q + 3] = v.w;
        }

        // lane scans codes [16*lane, 16*lane+16) ascending -> per-lane first-occurrence kept
        float bestv = FLT_MAX; int bj = 0x7fffffff;
        for (int t = 0; t < 16; ++t) {
            int j = lane * 16 + t;
            const float* c = cb + (size_t)j * CODE_DIM;
            float d0 = 0.f, d1 = 0.f, d2 = 0.f, d3 = 0.f;
#pragma unroll
            for (int k = 0; k < CODE_DIM; k += 4) {
                d0 = fmaf(xr[k + 0], c[k + 0], d0);
                d1 = fmaf(xr[k + 1], c[k + 1], d1);
                d2 = fmaf(xr[k + 2], c[k + 2], d2);
                d3 = fmaf(xr[k + 3], c[k + 3], d3);
            }
            float dist = fmaf(-2.f, (d0 + d1) + (d2 + d3), cnorm[j]);
            if (dist < bestv) { bestv = dist; bj = j; }
        }
        // cross-lane argmin with lowest-index tie-break
#pragma unroll
        for (int m = 1; m <= 32; m <<= 1) {
            float ob = __shfl_xor(bestv, m, 64);
            int   oj = __shfl_xor(bj, m, 64);
            bool take = (ob < bestv) || (ob == bestv && oj < bj);
            if (take) { bestv = ob; bj = oj; }
        }

        if (bj != oldj) {
            // rewrite out row (16 lanes x float4) and patch counts once
            if (lane < 16) {
                *reinterpret_cast<float4*>(out + (size_t)row * CODE_DIM + lane * 4) =
                    *reinterpret_cast<const float4*>(cb + (size_t)bj * CODE_DIM + lane * 4);
            }
            if (lane == 0) {
                atomicAdd(&counts[bj], 1u);
                atomicAdd(&counts[oldj], (unsigned)-1);
            }
        }
    }
}

__global__ void finalize_kernel(const unsigned int* __restrict__ counts,
                                const float* __restrict__ loss_sum,
                                float* __restrict__ out)
{
    __shared__ float red[NB_CODE];
    int t = threadIdx.x;
    float p = (float)counts[t] / (float)NROWS;
    red[t] = p * logf(p + 1e-7f);
    __syncthreads();
    for (int s = NB_CODE / 2; s > 0; s >>= 1) {
        if (t < s) red[t] += red[t + s];
        __syncthreads();
    }
    if (t == 0) {
        out[NTC + 0] = *loss_sum / (float)NTC;
        out[NTC + 1] = expf(-red[0]);
    }
}

extern "C" void kernel_launch(void* const* d_in, const int* in_sizes, int n_in,
                              void* d_out, int out_size, void* d_ws, size_t ws_size,
                              hipStream_t stream) {
    const float* x  = (const float*)d_in[0];
    const float* cb = (const float*)d_in[1];
    float* out = (float*)d_out;
    float* ws = (float*)d_ws;

    unsigned flag_cap = 0;
    size_t words = ws_size / 4;
    if (words > (size_t)W_FLAGLIST) flag_cap = (unsigned)(words - W_FLAGLIST);
    if (flag_cap > NROWS) flag_cap = NROWS;

    // zero counts + loss + flagcnt each call (ws not re-poisoned between replays)
    hipMemsetAsync(d_ws, 0, 1028 * sizeof(float), stream);

    prep_kernel<<<NB_CODE / 256, 256, 0, stream>>>(cb, ws);
    vq_mfma_kernel<<<NROWS / 256, 256, 0, stream>>>(x, cb, ws, out, flag_cap);
    fixup_kernel<<<256, 256, 0, stream>>>(x, cb, ws, out, flag_cap);
    finalize_kernel<<<1, NB_CODE, 0, stream>>>((unsigned int*)ws, ws + W_LOSS, out);
}